// Round 11
// baseline (210.039 us; speedup 1.0000x reference)
//
#include <hip/hip_runtime.h>
#include <hip/hip_bf16.h>

#define N_ROWS 8192
#define D_DIM  512
#define NSTEPS 8    // K-steps of BK=64

typedef __attribute__((ext_vector_type(4))) int   i32x4;
typedef __attribute__((ext_vector_type(8))) int   i32x8;
typedef __attribute__((ext_vector_type(16))) float f32x16;

// One wave per row-index i: L2-normalize cxr_i and ehr_i, write fp8 e4m3,
// and compute diag_i = dot(cxr_i,ehr_i)*ia*ib/temp (full fp32) in one pass.
__global__ void normdiag_kernel(const float* __restrict__ cxr, const float* __restrict__ ehr,
                                unsigned char* __restrict__ Ab, unsigned char* __restrict__ Bb,
                                const float* __restrict__ temp, float* __restrict__ dg) {
    const int row = blockIdx.x * 4 + (threadIdx.x >> 6);
    const int lane = threadIdx.x & 63;
    const float4* a4 = (const float4*)(cxr + (size_t)row * D_DIM + lane * 8);
    const float4* b4 = (const float4*)(ehr + (size_t)row * D_DIM + lane * 8);
    float4 a0 = a4[0], a1 = a4[1];
    float4 b0 = b4[0], b1 = b4[1];
    float sa = a0.x*a0.x + a0.y*a0.y + a0.z*a0.z + a0.w*a0.w
             + a1.x*a1.x + a1.y*a1.y + a1.z*a1.z + a1.w*a1.w;
    float sb = b0.x*b0.x + b0.y*b0.y + b0.z*b0.z + b0.w*b0.w
             + b1.x*b1.x + b1.y*b1.y + b1.z*b1.z + b1.w*b1.w;
    float dt = a0.x*b0.x + a0.y*b0.y + a0.z*b0.z + a0.w*b0.w
             + a1.x*b1.x + a1.y*b1.y + a1.z*b1.z + a1.w*b1.w;
#pragma unroll
    for (int s = 1; s < 64; s <<= 1) {
        sa += __shfl_xor(sa, s);
        sb += __shfl_xor(sb, s);
        dt += __shfl_xor(dt, s);
    }
    const float ia = 1.0f / sqrtf(fmaxf(sa, 1e-16f));
    const float ib = 1.0f / sqrtf(fmaxf(sb, 1e-16f));
    if (lane == 0) dg[row] = dt * ia * ib / temp[0];
    float va[8] = {a0.x, a0.y, a0.z, a0.w, a1.x, a1.y, a1.z, a1.w};
    float vb[8] = {b0.x, b0.y, b0.z, b0.w, b1.x, b1.y, b1.z, b1.w};
    int aw0 = __builtin_amdgcn_cvt_pk_fp8_f32(va[0]*ia, va[1]*ia, 0, false);
    aw0     = __builtin_amdgcn_cvt_pk_fp8_f32(va[2]*ia, va[3]*ia, aw0, true);
    int aw1 = __builtin_amdgcn_cvt_pk_fp8_f32(va[4]*ia, va[5]*ia, 0, false);
    aw1     = __builtin_amdgcn_cvt_pk_fp8_f32(va[6]*ia, va[7]*ia, aw1, true);
    int bw0 = __builtin_amdgcn_cvt_pk_fp8_f32(vb[0]*ib, vb[1]*ib, 0, false);
    bw0     = __builtin_amdgcn_cvt_pk_fp8_f32(vb[2]*ib, vb[3]*ib, bw0, true);
    int bw1 = __builtin_amdgcn_cvt_pk_fp8_f32(vb[4]*ib, vb[5]*ib, 0, false);
    bw1     = __builtin_amdgcn_cvt_pk_fp8_f32(vb[6]*ib, vb[7]*ib, bw1, true);
    *(int2*)(Ab + (size_t)row * D_DIM + lane * 8) = make_int2(aw0, aw1);
    *(int2*)(Bb + (size_t)row * D_DIM + lane * 8) = make_int2(bw0, bw1);
}

// fp8 128x128 GEMM with ZERO LDS operands and ZERO K-loop barriers:
// each lane loads its MFMA fragments global->VGPR (dwordx4 pairs directly into
// the i32x8 operand halves), double-buffered one K-step ahead. Waves are fully
// independent until the epilogue -> latency hidden by ILP + unsynchronized TLP.
// 4 waves (2x2), wave tile 64x64, acc[2][2] f32x16 = 64 VGPR, total ~146.
// Epilogue: exp((cos-1)/T), diag zeroed, row/col sums -> global atomics.
__global__ __launch_bounds__(256, 3) void gemm_lse_kernel(
        const unsigned char* __restrict__ A, const unsigned char* __restrict__ B,
        const float* __restrict__ temp,
        float* __restrict__ row_sum, float* __restrict__ col_sum) {
    __shared__ float rs_l[128];
    __shared__ float cs_l[128];

    const int tid = threadIdx.x;
    const int lane = tid & 63;
    const int wid = tid >> 6;                 // 4 waves
    const int bm = blockIdx.x & 63;           // bm-major: consecutive blocks
    const int bn = blockIdx.x >> 6;           // share the B panel in L2
    const int wm = wid >> 1, wn = wid & 1;    // wave tile 64x64

    if (tid < 128) rs_l[tid] = 0.f;
    else           cs_l[tid - 128] = 0.f;

    const int c31 = lane & 31, h2 = lane >> 5;

    // operand row pointers (fp8, row stride 512 B); lane covers row base+c31,
    // bytes [h2*32, h2*32+32) of each 64-byte K-step (validated layout r7-r10)
    const unsigned char* rA0 = A + (size_t)(bm * 128 + wm * 64 + c31) * D_DIM;
    const unsigned char* rA1 = rA0 + 32 * D_DIM;
    const unsigned char* rB0 = B + (size_t)(bn * 128 + wn * 64 + c31) * D_DIM;
    const unsigned char* rB1 = rB0 + 32 * D_DIM;

    i32x8 Af[2][2], Bf[2][2];
    f32x16 acc[2][2] = {};
    const int sc = 0x7F7F7F7F;   // E8M0 127 -> scale 1.0 for any opsel

    // load 32 B straight into the two halves of an i32x8 operand (no movs)
#define LD(dst, ptr, off) do { \
    *((i32x4*)&(dst))     = *(const i32x4*)((ptr) + (off)); \
    *((i32x4*)&(dst) + 1) = *(const i32x4*)((ptr) + (off) + 16); } while (0)

    // prologue: fragments for step 0
    {
        const int k0 = h2 * 32;
        LD(Af[0][0], rA0, k0); LD(Af[0][1], rA1, k0);
        LD(Bf[0][0], rB0, k0); LD(Bf[0][1], rB1, k0);
    }

#pragma unroll
    for (int s = 0; s < NSTEPS; ++s) {
        const int cb = s & 1, nb = cb ^ 1;
        if (s + 1 < NSTEPS) {
            const int k0 = (s + 1) * 64 + h2 * 32;
            LD(Af[nb][0], rA0, k0); LD(Af[nb][1], rA1, k0);
            LD(Bf[nb][0], rB0, k0); LD(Bf[nb][1], rB1, k0);
        }
#pragma unroll
        for (int mi = 0; mi < 2; ++mi)
#pragma unroll
            for (int ni = 0; ni < 2; ++ni)
                acc[mi][ni] = __builtin_amdgcn_mfma_scale_f32_32x32x64_f8f6f4(
                    Af[cb][mi], Bf[cb][ni], acc[mi][ni], 0, 0, 0, sc, 0, sc);
    }

    // ---- epilogue: exp + masked diag + row/col reduction ----
    // C/D 32x32 layout: col = lane&31, row = (reg&3) + 8*(reg>>2) + 4*(lane>>5)
    const float invT = 1.0f / temp[0];
    const bool diagBlk = (bm == bn);
    float colpart[2] = {0.f, 0.f};

#pragma unroll
    for (int mi = 0; mi < 2; ++mi) {
        float rowpart[16];
#pragma unroll
        for (int r = 0; r < 16; ++r) rowpart[r] = 0.f;
#pragma unroll
        for (int ni = 0; ni < 2; ++ni) {
            f32x16 a = acc[mi][ni];
#pragma unroll
            for (int r = 0; r < 16; ++r) {
                float e = __expf((a[r] - 1.0f) * invT);
                if (diagBlk) {
                    int grow = wm * 64 + mi * 32 + (r & 3) + 8 * (r >> 2) + 4 * h2;
                    int gcol = wn * 64 + ni * 32 + c31;
                    if (grow == gcol) e = 0.f;
                }
                rowpart[r] += e;
                colpart[ni] += e;
            }
        }
#pragma unroll
        for (int r = 0; r < 16; ++r) {
            float v = rowpart[r];
            v += __shfl_xor(v, 1);
            v += __shfl_xor(v, 2);
            v += __shfl_xor(v, 4);
            v += __shfl_xor(v, 8);
            v += __shfl_xor(v, 16);
            if (c31 == 0)
                atomicAdd(&rs_l[wm * 64 + mi * 32 + (r & 3) + 8 * (r >> 2) + 4 * h2], v);
        }
    }
#pragma unroll
    for (int ni = 0; ni < 2; ++ni) {
        float v = colpart[ni];
        v += __shfl_xor(v, 32);
        if (h2 == 0) atomicAdd(&cs_l[wn * 64 + ni * 32 + c31], v);
    }
    __syncthreads();
    if (tid < 128) atomicAdd(&row_sum[bm * 128 + tid], rs_l[tid]);
    else           atomicAdd(&col_sum[bn * 128 + (tid - 128)], cs_l[tid - 128]);
}

// loss = mean_i [ 2M + log(rs_i) + log(cs_i) - 2*diag_i ],  M = 1/temp
__global__ void finalize_kernel(const float* __restrict__ rs, const float* __restrict__ cs,
                                const float* __restrict__ dg, const float* __restrict__ temp,
                                float* __restrict__ out) {
    const float M = 1.0f / temp[0];
    float acc = 0.f;
    for (int i = threadIdx.x; i < N_ROWS; i += 256)
        acc += 2.f * M + __logf(rs[i]) + __logf(cs[i]) - 2.f * dg[i];
#pragma unroll
    for (int s = 1; s < 64; s <<= 1) acc += __shfl_xor(acc, s);
    __shared__ float wsum[4];
    if ((threadIdx.x & 63) == 0) wsum[threadIdx.x >> 6] = acc;
    __syncthreads();
    if (threadIdx.x == 0)
        out[0] = (wsum[0] + wsum[1] + wsum[2] + wsum[3]) / (float)N_ROWS;
}

extern "C" void kernel_launch(void* const* d_in, const int* in_sizes, int n_in,
                              void* d_out, int out_size, void* d_ws, size_t ws_size,
                              hipStream_t stream) {
    const float* cxr = (const float*)d_in[0];
    const float* ehr = (const float*)d_in[1];
    const float* temp = (const float*)d_in[2];
    float* out = (float*)d_out;

    char* ws = (char*)d_ws;
    unsigned char* Ab = (unsigned char*)ws;                        // 4 MB
    unsigned char* Bb = (unsigned char*)(ws + 4u * 1024 * 1024);   // 4 MB
    float* rs = (float*)(ws + 8u * 1024 * 1024);
    float* cs = rs + N_ROWS;
    float* dg = cs + N_ROWS;

    hipMemsetAsync(rs, 0, 2 * N_ROWS * sizeof(float), stream);
    normdiag_kernel<<<dim3(N_ROWS / 4), 256, 0, stream>>>(cxr, ehr, Ab, Bb, temp, dg);
    gemm_lse_kernel<<<dim3(64 * 64), 256, 0, stream>>>(Ab, Bb, temp, rs, cs);
    finalize_kernel<<<1, 256, 0, stream>>>(rs, cs, dg, temp, out);
}